// Round 2
// baseline (29724.640 us; speedup 1.0000x reference)
//
#include <hip/hip_runtime.h>

// RNNModel: 2-layer LSTM (B=64,T=400,E=H=500) + MLP head (800->100->2).
// Round 2: weight-stationary VGPR scheme.
//  - 256 blocks (1/CU), persistent, grid barrier per step (401 steps, pipelined layers).
//  - block = (layer L, batch-tile of 16, unit-tile of 16) -> 64 cols (16 units x 4 gates).
//  - lane c = tid&63 owns one col; wave w = tid>>6 owns K-chunk [w*125, w*125+125).
//    Each thread holds its 125 weights in VGPRs (loaded once).
//  - x staged transposed in LDS [k][b] (16 f32 per k); K-loop reads x via
//    uniform-address ds_read_b128 (broadcast) with immediate offsets.
//  - f32 partials per 125-chunk (same serial fmaf order as round 1), f64 combine
//    across 8 chunks + f64 gates; cell state c lives in registers (bit-identical numerics).

#define NBLK 256
#define NTHR 512
#define Bn 64
#define Tn 400
#define Hn 500

// ws byte offsets
#define OFF_H1 0            // float [2][64*500]
#define OFF_H2 256000       // float [2][64*500]
#define OFF_D1 512000       // float [64*800]
#define OFF_D2 716800       // float [64*100]
#define OFF_CNT 742400      // unsigned counter

__device__ __forceinline__ void gbar(unsigned* cnt, unsigned target) {
    __syncthreads();
    if (threadIdx.x == 0) {
        __threadfence();
        unsigned prevv = __hip_atomic_fetch_add(cnt, 1u, __ATOMIC_ACQ_REL,
                                                __HIP_MEMORY_SCOPE_AGENT);
        if (prevv + 1u != target) {
            while (__hip_atomic_load(cnt, __ATOMIC_ACQUIRE,
                                     __HIP_MEMORY_SCOPE_AGENT) < target) {
                __builtin_amdgcn_s_sleep(2);
            }
        }
    }
    __syncthreads();
}

extern "C" __global__ void __launch_bounds__(NTHR, 2)
rnn_all(const int* __restrict__ X, const float* __restrict__ embed,
        const float* __restrict__ k1, const float* __restrict__ b1,
        const float* __restrict__ k2, const float* __restrict__ b2,
        const float* __restrict__ w1, const float* __restrict__ bw1,
        const float* __restrict__ w2, const float* __restrict__ bw2,
        const float* __restrict__ wpm, const float* __restrict__ bpv,
        float* __restrict__ out, char* __restrict__ ws)
{
    __shared__ float s_x[16000];   // [k<1000][b<16] transposed input
    __shared__ float s_P[8192];    // [chunk<8][c<64][b'<16] partials (b swizzled)

    float* h1b = (float*)(ws + OFF_H1);
    float* h2b = (float*)(ws + OFF_H2);
    float* d1p = (float*)(ws + OFF_D1);
    float* d2p = (float*)(ws + OFF_D2);
    unsigned* cnt = (unsigned*)(ws + OFF_CNT);

    const int bid = blockIdx.x;
    const int tid = threadIdx.x;
    const int L = bid >> 7;            // layer
    const int btile = (bid >> 5) & 3;  // 4 batch tiles of 16
    const int ut = bid & 31;           // 32 unit tiles of 16
    const int b0 = btile * 16;

    const int c = tid & 63;            // column lane: c = g*16 + ul
    const int w = tid >> 6;            // wave id = K chunk (125 each)
    const int bl = c & 15;             // staging: batch lane
    const int kq = c >> 4;             // staging: k-quad within 16
    const int g = c >> 4;              // gate index 0..3 (i,j,f,o)
    const int ul = c & 15;             // unit within tile
    const int colc = g * 500 + min(ut * 16 + ul, 499);  // clamped weight column

    const float* Wm = L ? k2 : k1;     // [1000][2000]
    const float* bv = L ? b2 : b1;

    // ---- one-time weight preload: 125 floats per thread into VGPRs ----
    float wreg[125];
    {
        const float* wp = Wm + (size_t)(w * 125) * 2000 + colc;
        #pragma unroll
        for (int i = 0; i < 125; ++i) wreg[i] = wp[(size_t)i * 2000];
    }

    // ---- gate-thread state (tid < 256): thread owns (batch gb, unit gu) ----
    const int gb = tid >> 4;           // 0..15 (only meaningful for tid<256)
    const int gu = tid & 15;
    const int ug = ut * 16 + gu;       // global unit index
    const bool gvalid = (tid < 256) && (ug < Hn);
    float bi_ = gvalid ? bv[ug] : 0.f;
    float bj_ = gvalid ? bv[500 + ug] : 0.f;
    float bf_ = gvalid ? bv[1000 + ug] : 0.f;
    float bo_ = gvalid ? bv[1500 + ug] : 0.f;
    double cstate = 0.0;

    unsigned ep = 0;

    for (int s = 0; s <= Tn; ++s) {
        const int cur = s & 1;
        const int prv = cur ^ 1;
        const float* h1prev = h1b + prv * 32000;
        const float* h2prev = h2b + prv * 32000;
        float* hout = (L ? h2b : h1b) + cur * 32000;
        const bool active = L ? (s >= 1) : (s < Tn);

        if (active) {
            const int t = L ? (s - 1) : s;
            // per-lane staging source rows (batch bl)
            const float* rowA;
            const float* rowB;
            if (L == 0) {
                const int id = X[(b0 + bl) * Tn + t];
                rowA = embed + (size_t)id * 500;
                rowB = h1prev + (b0 + bl) * 500;
            } else {
                rowA = h1prev + (b0 + bl) * 500;
                rowB = h2prev + (b0 + bl) * 500;
            }
            // ---- stage x transposed: wave w covers k in [w*128, w*128+128) ----
            #pragma unroll
            for (int it = 0; it < 8; ++it) {
                const int k = w * 128 + it * 16 + 4 * kq;
                if (k < 1000) {
                    const float* src = (k < 500) ? (rowA + k) : (rowB + (k - 500));
                    const float4 v = *(const float4*)src;
                    float* d = &s_x[k * 16 + bl];
                    d[0] = v.x; d[16] = v.y; d[32] = v.z; d[48] = v.w;
                }
            }
            __syncthreads();

            // ---- K-loop: chunk w, col c; 125 iters, fully unrolled ----
            float4 a0 = {0.f, 0.f, 0.f, 0.f};
            float4 a1 = a0, a2 = a0, a3 = a0;
            const float* xb = &s_x[w * 125 * 16];
            #pragma unroll
            for (int i = 0; i < 125; ++i) {
                const float wv = wreg[i];
                const float4 x0 = *(const float4*)(xb + i * 16 + 0);
                const float4 x1 = *(const float4*)(xb + i * 16 + 4);
                const float4 x2 = *(const float4*)(xb + i * 16 + 8);
                const float4 x3 = *(const float4*)(xb + i * 16 + 12);
                a0.x = fmaf(wv, x0.x, a0.x);
                a0.y = fmaf(wv, x0.y, a0.y);
                a0.z = fmaf(wv, x0.z, a0.z);
                a0.w = fmaf(wv, x0.w, a0.w);
                a1.x = fmaf(wv, x1.x, a1.x);
                a1.y = fmaf(wv, x1.y, a1.y);
                a1.z = fmaf(wv, x1.z, a1.z);
                a1.w = fmaf(wv, x1.w, a1.w);
                a2.x = fmaf(wv, x2.x, a2.x);
                a2.y = fmaf(wv, x2.y, a2.y);
                a2.z = fmaf(wv, x2.z, a2.z);
                a2.w = fmaf(wv, x2.w, a2.w);
                a3.x = fmaf(wv, x3.x, a3.x);
                a3.y = fmaf(wv, x3.y, a3.y);
                a3.z = fmaf(wv, x3.z, a3.z);
                a3.w = fmaf(wv, x3.w, a3.w);
            }
            // ---- write partials (swizzled quad rotation to spread banks) ----
            {
                const int pb = (w * 64 + c) * 16;
                *(float4*)&s_P[pb + 4 * ((0 + c) & 3)] = a0;
                *(float4*)&s_P[pb + 4 * ((1 + c) & 3)] = a1;
                *(float4*)&s_P[pb + 4 * ((2 + c) & 3)] = a2;
                *(float4*)&s_P[pb + 4 * ((3 + c) & 3)] = a3;
            }
            __syncthreads();

            // ---- gate phase: f64 combine of 8 chunks + LSTM cell ----
            if (gvalid) {
                double z[4];
                #pragma unroll
                for (int gg = 0; gg < 4; ++gg) {
                    const int cc = gg * 16 + gu;
                    double zz = 0.0;
                    #pragma unroll
                    for (int q = 0; q < 8; ++q)
                        zz += (double)s_P[(q * 64 + cc) * 16 + ((gb + 4 * cc) & 15)];
                    z[gg] = zz;
                }
                const double zi = z[0] + (double)bi_;
                const double zj = z[1] + (double)bj_;
                const double zf = z[2] + (double)bf_;
                const double zo = z[3] + (double)bo_;
                const double gi = 1.0 / (1.0 + exp(-zi));
                const double gf = 1.0 / (1.0 + exp(-(zf + 1.0)));
                const double go = 1.0 / (1.0 + exp(-zo));
                cstate = gf * cstate + gi * tanh(zj);
                hout[(b0 + gb) * 500 + ug] = (float)(go * tanh(cstate));
            }
        }
        ++ep;
        gbar(cnt, ep * NBLK);
    }

    // ---- dense head (f64 accumulation), same as validated round 1 ----
    const float* last = h2b + (Tn & 1) * 32000;  // h2 at t=399 -> phase 0
    if (tid < 200) {
        int o = bid * 200 + tid;                  // 256*200 = 64*800
        int b = o / 800, j = o - b * 800;
        const float* lr = last + b * 500;
        double acc = 0;
        for (int kk = 0; kk < 500; ++kk)
            acc += (double)lr[kk] * (double)w1[(size_t)kk * 800 + j];
        acc += (double)bw1[j];
        d1p[b * 800 + j] = (float)fmax(acc, 0.0);
    }
    ++ep;
    gbar(cnt, ep * NBLK);
    if (tid < 25) {
        int o = bid * 25 + tid;                   // 256*25 = 64*100
        int b = o / 100, j = o - b * 100;
        const float* dr = d1p + b * 800;
        double acc = 0;
        for (int kk = 0; kk < 800; ++kk)
            acc += (double)dr[kk] * (double)w2[(size_t)kk * 100 + j];
        acc += (double)bw2[j];
        d2p[b * 100 + j] = (float)fmax(acc, 0.0);
    }
    ++ep;
    gbar(cnt, ep * NBLK);
    if (bid == 0 && tid < 128) {
        int b = tid >> 1, cc = tid & 1;
        const float* dr = d2p + b * 100;
        double acc = 0;
        for (int kk = 0; kk < 100; ++kk)
            acc += (double)dr[kk] * (double)wpm[kk * 2 + cc];
        acc += (double)bpv[cc];
        out[b * 2 + cc] = (float)acc;
    }
}

extern "C" void kernel_launch(void* const* d_in, const int* in_sizes, int n_in,
                              void* d_out, int out_size, void* d_ws, size_t ws_size,
                              hipStream_t stream) {
    const int* X = (const int*)d_in[0];
    const float* embed = (const float*)d_in[1];
    const float* k1 = (const float*)d_in[2];
    const float* b1 = (const float*)d_in[3];
    const float* k2 = (const float*)d_in[4];
    const float* b2 = (const float*)d_in[5];
    const float* w1 = (const float*)d_in[6];
    const float* bw1 = (const float*)d_in[7];
    const float* w2 = (const float*)d_in[8];
    const float* bw2 = (const float*)d_in[9];
    const float* wpm = (const float*)d_in[10];
    const float* bpv = (const float*)d_in[11];

    // zero h buffers + barrier counter (captured in graph -> clean every replay)
    hipMemsetAsync(d_ws, 0, 512000, stream);
    hipMemsetAsync((char*)d_ws + OFF_CNT, 0, 64, stream);

    rnn_all<<<NBLK, NTHR, 0, stream>>>(X, embed, k1, b1, k2, b2, w1, bw1,
                                       w2, bw2, wpm, bpv,
                                       (float*)d_out, (char*)d_ws);
}